// Round 1
// baseline (306.389 us; speedup 1.0000x reference)
//
#include <hip/hip_runtime.h>
#include <math.h>

#define HID 512

// Kernel 1: one wave (64 lanes) per output element i in [0, 512).
// Each wave computes 6 dot products of length 512:
//   rows i, 512+i, 1024+i of w_ih (against x = emb[token])
//   rows i, 512+i, 1024+i of w_hh (against h)
// then applies the GRU cell nonlinearity and writes h_new[i] to ws.
__global__ __launch_bounds__(256) void gru_matvec_kernel(
    const int*   __restrict__ tok,
    const float* __restrict__ hidden,   // [512]
    const float* __restrict__ emb,      // [128000, 512]
    const float* __restrict__ w_ih,     // [1536, 512]
    const float* __restrict__ w_hh,     // [1536, 512]
    const float* __restrict__ b_ih,     // [1536]
    const float* __restrict__ b_hh,     // [1536]
    float*       __restrict__ hnew)     // [512] out (workspace)
{
    const int lane = threadIdx.x & 63;
    const int wid  = threadIdx.x >> 6;          // wave in block, 0..3
    const int i    = blockIdx.x * 4 + wid;      // output index 0..511

    const float* __restrict__ x = emb + (size_t)tok[0] * HID;

    float a0 = 0.f, a1 = 0.f, a2 = 0.f;   // w_ih rows r,z,n  dot x
    float a3 = 0.f, a4 = 0.f, a5 = 0.f;   // w_hh rows r,z,n  dot h

    #pragma unroll
    for (int p = 0; p < 2; ++p) {
        const int col = lane * 4 + p * 256;     // 64 lanes * 4 floats = 256 cols/pass
        const float4 xv = *(const float4*)(x + col);
        const float4 hv = *(const float4*)(hidden + col);

        const float4 wi0 = *(const float4*)(w_ih + (size_t)(0 * HID + i) * HID + col);
        const float4 wi1 = *(const float4*)(w_ih + (size_t)(1 * HID + i) * HID + col);
        const float4 wi2 = *(const float4*)(w_ih + (size_t)(2 * HID + i) * HID + col);
        const float4 wh0 = *(const float4*)(w_hh + (size_t)(0 * HID + i) * HID + col);
        const float4 wh1 = *(const float4*)(w_hh + (size_t)(1 * HID + i) * HID + col);
        const float4 wh2 = *(const float4*)(w_hh + (size_t)(2 * HID + i) * HID + col);

        a0 += wi0.x * xv.x + wi0.y * xv.y + wi0.z * xv.z + wi0.w * xv.w;
        a1 += wi1.x * xv.x + wi1.y * xv.y + wi1.z * xv.z + wi1.w * xv.w;
        a2 += wi2.x * xv.x + wi2.y * xv.y + wi2.z * xv.z + wi2.w * xv.w;
        a3 += wh0.x * hv.x + wh0.y * hv.y + wh0.z * hv.z + wh0.w * hv.w;
        a4 += wh1.x * hv.x + wh1.y * hv.y + wh1.z * hv.z + wh1.w * hv.w;
        a5 += wh2.x * hv.x + wh2.y * hv.y + wh2.z * hv.z + wh2.w * hv.w;
    }

    // wave (64-lane) reduction of the 6 partial sums
    #pragma unroll
    for (int off = 32; off > 0; off >>= 1) {
        a0 += __shfl_down(a0, off, 64);
        a1 += __shfl_down(a1, off, 64);
        a2 += __shfl_down(a2, off, 64);
        a3 += __shfl_down(a3, off, 64);
        a4 += __shfl_down(a4, off, 64);
        a5 += __shfl_down(a5, off, 64);
    }

    if (lane == 0) {
        const float gi_r = a0 + b_ih[i];
        const float gi_z = a1 + b_ih[HID + i];
        const float gi_n = a2 + b_ih[2 * HID + i];
        const float gh_r = a3 + b_hh[i];
        const float gh_z = a4 + b_hh[HID + i];
        const float gh_n = a5 + b_hh[2 * HID + i];

        const float r = 1.f / (1.f + expf(-(gi_r + gh_r)));
        const float z = 1.f / (1.f + expf(-(gi_z + gh_z)));
        const float n = tanhf(gi_n + r * gh_n);
        hnew[i] = (1.f - z) * n + z * hidden[i];
    }
}

// Kernel 2: single block of 512 threads. FC (OUT=2) + log-softmax.
__global__ __launch_bounds__(512) void fc_head_kernel(
    const float* __restrict__ hnew,   // [512]
    const float* __restrict__ fc_w,   // [2, 512]
    const float* __restrict__ fc_b,   // [2]
    float*       __restrict__ out)    // [2]
{
    const int t    = threadIdx.x;      // 0..511
    const int lane = t & 63;
    const int wid  = t >> 6;           // 0..7

    const float hv = hnew[t];
    float p0 = hv * fc_w[t];
    float p1 = hv * fc_w[HID + t];

    #pragma unroll
    for (int off = 32; off > 0; off >>= 1) {
        p0 += __shfl_down(p0, off, 64);
        p1 += __shfl_down(p1, off, 64);
    }

    __shared__ float s0[8], s1[8];
    if (lane == 0) { s0[wid] = p0; s1[wid] = p1; }
    __syncthreads();

    if (t == 0) {
        float l0 = fc_b[0], l1 = fc_b[1];
        #pragma unroll
        for (int k = 0; k < 8; ++k) { l0 += s0[k]; l1 += s1[k]; }
        const float m   = fmaxf(l0, l1);
        const float lse = m + logf(expf(l0 - m) + expf(l1 - m));
        out[0] = l0 - lse;
        out[1] = l1 - lse;
    }
}

extern "C" void kernel_launch(void* const* d_in, const int* in_sizes, int n_in,
                              void* d_out, int out_size, void* d_ws, size_t ws_size,
                              hipStream_t stream) {
    const int*   tok    = (const int*)  d_in[0];
    const float* hidden = (const float*)d_in[1];
    const float* emb    = (const float*)d_in[2];
    const float* w_ih   = (const float*)d_in[3];
    const float* w_hh   = (const float*)d_in[4];
    const float* b_ih   = (const float*)d_in[5];
    const float* b_hh   = (const float*)d_in[6];
    const float* fc_w   = (const float*)d_in[7];
    const float* fc_b   = (const float*)d_in[8];
    float*       out    = (float*)d_out;
    float*       hnew   = (float*)d_ws;   // 512 floats of scratch

    // 512 output elements, 1 wave each -> 128 blocks * 4 waves
    gru_matvec_kernel<<<128, 256, 0, stream>>>(tok, hidden, emb, w_ih, w_hh,
                                               b_ih, b_hh, hnew);
    fc_head_kernel<<<1, 512, 0, stream>>>(hnew, fc_w, fc_b, out);
}